// Round 1
// baseline (601.157 us; speedup 1.0000x reference)
//
#include <hip/hip_runtime.h>
#include <hip/hip_bf16.h>

// Attention fwd: B=4 H=16 S=2048 D=128, fp32 in/out, scale = 128^-0.5.
// Strategy: pre-transpose V -> VT[bh][d][s] (bf16, in d_ws), then flash-attention
// with mfma_f32_16x16x32_bf16. Block = 256 thr = 4 waves, 64 Q-rows/block,
// KV tiles of 64 keys. Each wave owns a 16-row Q strip: softmax reductions are
// 16-lane shfls; P round-trips through LDS (C-layout -> A-layout) wave-locally.
// All LDS row strides are odd multiples of 16B -> ds_read_b128 frags 2-way free.

#define SEQ 2048
#define DH  128
#define NBH 64          // B*H
#define BM  64          // Q rows per block
#define BN  64          // keys per KV iteration
#define QK_LD 136       // bf16 elems per row for Q/K tiles (128+8): 272B rows
#define VT_LD 72        // (64+8): 144B rows
#define P_LD  72

typedef __attribute__((ext_vector_type(8))) short short8;
typedef __attribute__((ext_vector_type(4))) float f32x4;

#if __has_builtin(__builtin_amdgcn_exp2f)
#define EXP2F(x) __builtin_amdgcn_exp2f(x)
#else
#define EXP2F(x) exp2f(x)
#endif

// softmax scale folded with log2(e): exp(s*scale) == exp2(s*CS)
#define CS (0.08838834764831845f * 1.44269504088896340736f)

__device__ __forceinline__ unsigned int f2bf(float f) {
    union { float f; unsigned int u; } cv;
    cv.f = f;
    unsigned int u = cv.u;
    return (u + 0x7FFFu + ((u >> 16) & 1u)) >> 16;   // RNE bf16
}

// ---- V transpose + bf16 convert: V[bh][s][d] (f32) -> VT[bh][d][s] (bf16) ----
__global__ __launch_bounds__(256) void transpose_v_kernel(
        const float* __restrict__ v, unsigned short* __restrict__ vt) {
    __shared__ float tile[64][65];          // +1 pad: transposed reads 2-way free
    const int bh = blockIdx.z;
    const int s0 = blockIdx.x * 64;
    const int d0 = blockIdx.y * 64;
    const int tid = threadIdx.x;
    const float* src = v + ((size_t)bh * SEQ + s0) * DH + d0;
#pragma unroll
    for (int i = 0; i < 4; ++i) {
        int id  = tid + 256 * i;
        int row = id >> 4;                  // 0..63 key
        int c4  = (id & 15) << 2;           // 0..60 d offset
        float4 val = *reinterpret_cast<const float4*>(src + row * DH + c4);
        tile[row][c4 + 0] = val.x;
        tile[row][c4 + 1] = val.y;
        tile[row][c4 + 2] = val.z;
        tile[row][c4 + 3] = val.w;
    }
    __syncthreads();
    unsigned short* dst = vt + ((size_t)bh * DH + d0) * SEQ + s0;
#pragma unroll
    for (int i = 0; i < 2; ++i) {
        int id = tid + 256 * i;
        int dd = id >> 3;                   // 0..63 d row
        int kc = (id & 7) << 3;             // key chunk of 8
        uint4 pk;
        unsigned int* pw = reinterpret_cast<unsigned int*>(&pk);
#pragma unroll
        for (int j = 0; j < 4; ++j) {
            unsigned int lo = f2bf(tile[kc + 2 * j    ][dd]);
            unsigned int hi = f2bf(tile[kc + 2 * j + 1][dd]);
            pw[j] = lo | (hi << 16);
        }
        *reinterpret_cast<uint4*>(dst + (size_t)dd * SEQ + kc) = pk;   // 16B coalesced
    }
}

// ---- flash attention ----
__global__ __launch_bounds__(256) void fattn_kernel(
        const float* __restrict__ q, const float* __restrict__ k,
        const unsigned short* __restrict__ vt, float* __restrict__ out) {
    __shared__ unsigned short Qs[BM * QK_LD];   // [q_row][d]
    __shared__ unsigned short Ks[BN * QK_LD];   // [key][d]
    __shared__ unsigned short Vs[DH * VT_LD];   // [d][key]  (transposed V tile)
    __shared__ unsigned short Ps[BM * P_LD];    // [q_row][key]

    const int bh   = blockIdx.y;
    const int q0   = blockIdx.x * BM;
    const int tid  = threadIdx.x;
    const int w    = tid >> 6;      // wave 0..3
    const int lane = tid & 63;
    const int l15  = lane & 15;
    const int quad = lane >> 4;

    // ---- stage Q tile (64 x 128), f32 -> bf16 ----
    const float* qbase = q + ((size_t)bh * SEQ + q0) * DH;
#pragma unroll
    for (int i = 0; i < 8; ++i) {
        int id  = tid + 256 * i;
        int row = id >> 5;                  // 0..63
        int c4  = (id & 31) << 2;           // 0..124
        float4 val = *reinterpret_cast<const float4*>(qbase + row * DH + c4);
        uint2 pk;
        pk.x = f2bf(val.x) | (f2bf(val.y) << 16);
        pk.y = f2bf(val.z) | (f2bf(val.w) << 16);
        *reinterpret_cast<uint2*>(&Qs[row * QK_LD + c4]) = pk;
    }

    f32x4 o[8];
#pragma unroll
    for (int t = 0; t < 8; ++t) o[t] = (f32x4){0.f, 0.f, 0.f, 0.f};
    float mrow[4] = {-1e30f, -1e30f, -1e30f, -1e30f};
    float lrow[4] = {0.f, 0.f, 0.f, 0.f};

    const float*          kbase = k  + (size_t)bh * SEQ * DH;
    const unsigned short* vbase = vt + (size_t)bh * DH * SEQ;

    for (int kt = 0; kt < SEQ / BN; ++kt) {
        const int k0 = kt * BN;
        // ---- stage K tile (64 keys x 128 d), f32 -> bf16 ----
#pragma unroll
        for (int i = 0; i < 8; ++i) {
            int id  = tid + 256 * i;
            int row = id >> 5;
            int c4  = (id & 31) << 2;
            float4 val = *reinterpret_cast<const float4*>(kbase + (size_t)(k0 + row) * DH + c4);
            uint2 pk;
            pk.x = f2bf(val.x) | (f2bf(val.y) << 16);
            pk.y = f2bf(val.z) | (f2bf(val.w) << 16);
            *reinterpret_cast<uint2*>(&Ks[row * QK_LD + c4]) = pk;
        }
        // ---- stage VT tile (128 d x 64 keys), already bf16 ----
#pragma unroll
        for (int i = 0; i < 4; ++i) {
            int id = tid + 256 * i;
            int dd = id >> 3;               // 0..127
            int kc = (id & 7) << 3;         // 0..56
            uint4 val = *reinterpret_cast<const uint4*>(vbase + (size_t)dd * SEQ + k0 + kc);
            *reinterpret_cast<uint4*>(&Vs[dd * VT_LD + kc]) = val;
        }
        __syncthreads();

        // ---- S = Q K^T : wave w computes rows [w*16, w*16+16) x 64 keys ----
        f32x4 acc[4];
#pragma unroll
        for (int t = 0; t < 4; ++t) acc[t] = (f32x4){0.f, 0.f, 0.f, 0.f};
#pragma unroll
        for (int kk = 0; kk < 4; ++kk) {
            const int koff = kk * 32 + quad * 8;
            short8 a = *reinterpret_cast<const short8*>(&Qs[(w * 16 + l15) * QK_LD + koff]);
#pragma unroll
            for (int t = 0; t < 4; ++t) {
                short8 b = *reinterpret_cast<const short8*>(&Ks[(t * 16 + l15) * QK_LD + koff]);
                acc[t] = __builtin_amdgcn_mfma_f32_16x16x32_bf16(a, b, acc[t], 0, 0, 0);
            }
        }

        // ---- online softmax (exp2 domain); row = w*16 + quad*4 + r ----
#pragma unroll
        for (int r = 0; r < 4; ++r) {
            float mx = fmaxf(fmaxf(acc[0][r], acc[1][r]), fmaxf(acc[2][r], acc[3][r]));
#pragma unroll
            for (int off = 1; off < 16; off <<= 1)
                mx = fmaxf(mx, __shfl_xor(mx, off));
            float mnew  = fmaxf(mrow[r], CS * mx);
            float alpha = EXP2F(mrow[r] - mnew);
            mrow[r] = mnew;
            float p[4];
            float ps = 0.f;
#pragma unroll
            for (int t = 0; t < 4; ++t) {
                p[t] = EXP2F(CS * acc[t][r] - mnew);
                ps += p[t];
            }
#pragma unroll
            for (int off = 1; off < 16; off <<= 1)
                ps += __shfl_xor(ps, off);
            lrow[r] = lrow[r] * alpha + ps;
#pragma unroll
            for (int t = 0; t < 8; ++t) o[t][r] *= alpha;
            const int prow = w * 16 + quad * 4 + r;
#pragma unroll
            for (int t = 0; t < 4; ++t)
                Ps[prow * P_LD + t * 16 + l15] = (unsigned short)f2bf(p[t]);
        }

        // ---- O += P V : A-frag from own P rows, B-frag from VT tile ----
#pragma unroll
        for (int kk = 0; kk < 2; ++kk) {
            const int koff = kk * 32 + quad * 8;
            short8 a = *reinterpret_cast<const short8*>(&Ps[(w * 16 + l15) * P_LD + koff]);
#pragma unroll
            for (int t = 0; t < 8; ++t) {
                short8 b = *reinterpret_cast<const short8*>(&Vs[(t * 16 + l15) * VT_LD + koff]);
                o[t] = __builtin_amdgcn_mfma_f32_16x16x32_bf16(a, b, o[t], 0, 0, 0);
            }
        }
        __syncthreads();   // protect K/V/P tiles before next iteration's staging
    }

    // ---- epilogue: normalize and store fp32 ----
    float* obase = out + ((size_t)bh * SEQ + q0) * DH;
#pragma unroll
    for (int r = 0; r < 4; ++r) {
        float inv = 1.0f / lrow[r];
        int row = w * 16 + quad * 4 + r;
#pragma unroll
        for (int t = 0; t < 8; ++t)
            obase[(size_t)row * DH + t * 16 + l15] = o[t][r] * inv;
    }
}

extern "C" void kernel_launch(void* const* d_in, const int* in_sizes, int n_in,
                              void* d_out, int out_size, void* d_ws, size_t ws_size,
                              hipStream_t stream) {
    const float* q = (const float*)d_in[0];
    const float* k = (const float*)d_in[1];
    const float* v = (const float*)d_in[2];
    float* out = (float*)d_out;
    unsigned short* vt = (unsigned short*)d_ws;   // 64*128*2048*2 = 32 MB

    transpose_v_kernel<<<dim3(SEQ / 64, DH / 64, NBH), dim3(256), 0, stream>>>(v, vt);
    fattn_kernel<<<dim3(SEQ / BM, NBH), dim3(256), 0, stream>>>(q, k, vt, out);
}